// Round 1
// baseline (3391.128 us; speedup 1.0000x reference)
//
#include <hip/hip_runtime.h>

// MetaLayer GNN: 2 node types (a,b), 3 edge types (aa, ab, bb)
// All fp32. One thread per edge / per node; weights via wave-uniform loads
// (scalarized to s_load); accumulators fully in VGPRs; aggregation fused
// into edge kernel via fp32 global atomics in workspace.

constexpr int NA = 100000;
constexpr int NB = 100000;
constexpr int NEDGE = 400000;
constexpr int DN = 64;   // node feat
constexpr int DE = 32;   // edge feat
constexpr int DH = 64;   // hidden

constexpr int WS_SUM = NA * DE;   // one sum buffer, floats
// ws layout (floats):
//   [0        , WS_SUM)   sum_a1  (ne_aa aggregated on ei_aa[0], for node a)
//   [WS_SUM   , 2*WS_SUM) sum_a2  (ne_ab aggregated on ei_ab[0], for node a)
//   [2*WS_SUM , 3*WS_SUM) sum_b1  (ne_ab aggregated on ei_ab[1], for node b)
//   [3*WS_SUM , 4*WS_SUM) sum_b2  (ne_bb aggregated on ei_bb[0], for node b)
//   [4*WS_SUM , +4*NA)    counts: cnt_a1[NA], cnt_a2[NA], cnt_b1[NA], cnt_b2[NA]
constexpr int WS_FLOATS = 4 * WS_SUM + 4 * NA;

__global__ __launch_bounds__(256) void zero_ws(float4* __restrict__ ws, int n4) {
    int i = blockIdx.x * 256 + threadIdx.x;
    int stride = gridDim.x * 256;
    for (; i < n4; i += stride) ws[i] = make_float4(0.f, 0.f, 0.f, 0.f);
}

__global__ __launch_bounds__(256) void edge_kernel(
    const float* __restrict__ x_a, const float* __restrict__ x_b,
    const int* __restrict__ ei_aa, const int* __restrict__ ei_ab, const int* __restrict__ ei_bb,
    const float* __restrict__ ea_aa, const float* __restrict__ ea_ab, const float* __restrict__ ea_bb,
    const float* __restrict__ We1, const float* __restrict__ be1,
    const float* __restrict__ We2, const float* __restrict__ be2,
    float* __restrict__ ne_out,   // d_out + 2*NA*DN, the 3 ne arrays back-to-back
    float* __restrict__ ws)
{
    constexpr int BPT = (NEDGE + 255) / 256;  // blocks per edge type
    const int k = blockIdx.x / BPT;           // edge type 0=aa 1=ab 2=bb (block-uniform)
    const int e = (blockIdx.x - k * BPT) * 256 + threadIdx.x;
    if (e >= NEDGE) return;

    const int*   ei = (k == 0) ? ei_aa : (k == 1) ? ei_ab : ei_bb;
    const float* ea = (k == 0) ? ea_aa : (k == 1) ? ea_ab : ea_bb;
    const float* x1 = (k == 2) ? x_b : x_a;   // src features
    const float* x2 = (k == 0) ? x_a : x_b;   // dst features
    const float* __restrict__ W1 = We1 + (size_t)k * (2 * DN + DE) * DH;
    const float* __restrict__ b1 = be1 + k * DH;
    const float* __restrict__ W2 = We2 + (size_t)k * DH * DE;
    const float* __restrict__ b2 = be2 + k * DE;

    const int src = ei[e];
    const int dst = ei[NEDGE + e];

    float h[DH];
#pragma unroll
    for (int j = 0; j < DH; j++) h[j] = b1[j];

    // ---- layer 1: h += concat(x1[src], x2[dst], ea[e]) @ W1 ----
    {
        const float4* row = (const float4*)(x1 + (size_t)src * DN);
        for (int c = 0; c < DN / 4; c++) {
            float4 v = row[c];
            const float* w = W1 + (size_t)(c * 4) * DH;
#pragma unroll
            for (int j = 0; j < DH; j++) h[j] = fmaf(v.x, w[j], h[j]);
#pragma unroll
            for (int j = 0; j < DH; j++) h[j] = fmaf(v.y, w[DH + j], h[j]);
#pragma unroll
            for (int j = 0; j < DH; j++) h[j] = fmaf(v.z, w[2 * DH + j], h[j]);
#pragma unroll
            for (int j = 0; j < DH; j++) h[j] = fmaf(v.w, w[3 * DH + j], h[j]);
        }
    }
    {
        const float4* row = (const float4*)(x2 + (size_t)dst * DN);
        for (int c = 0; c < DN / 4; c++) {
            float4 v = row[c];
            const float* w = W1 + (size_t)(DN + c * 4) * DH;
#pragma unroll
            for (int j = 0; j < DH; j++) h[j] = fmaf(v.x, w[j], h[j]);
#pragma unroll
            for (int j = 0; j < DH; j++) h[j] = fmaf(v.y, w[DH + j], h[j]);
#pragma unroll
            for (int j = 0; j < DH; j++) h[j] = fmaf(v.z, w[2 * DH + j], h[j]);
#pragma unroll
            for (int j = 0; j < DH; j++) h[j] = fmaf(v.w, w[3 * DH + j], h[j]);
        }
    }
    {
        const float4* row = (const float4*)(ea + (size_t)e * DE);
        for (int c = 0; c < DE / 4; c++) {
            float4 v = row[c];
            const float* w = W1 + (size_t)(2 * DN + c * 4) * DH;
#pragma unroll
            for (int j = 0; j < DH; j++) h[j] = fmaf(v.x, w[j], h[j]);
#pragma unroll
            for (int j = 0; j < DH; j++) h[j] = fmaf(v.y, w[DH + j], h[j]);
#pragma unroll
            for (int j = 0; j < DH; j++) h[j] = fmaf(v.z, w[2 * DH + j], h[j]);
#pragma unroll
            for (int j = 0; j < DH; j++) h[j] = fmaf(v.w, w[3 * DH + j], h[j]);
        }
    }

    // ---- relu ----
#pragma unroll
    for (int j = 0; j < DH; j++) h[j] = fmaxf(h[j], 0.f);

    // ---- layer 2: o = h @ W2 + b2 ----
    float o[DE];
#pragma unroll
    for (int j = 0; j < DE; j++) o[j] = b2[j];
#pragma unroll
    for (int i = 0; i < DH; i++) {
        float v = h[i];
        const float* w = W2 + (size_t)i * DE;
#pragma unroll
        for (int j = 0; j < DE; j++) o[j] = fmaf(v, w[j], o[j]);
    }

    // ---- write ne to output ----
    float* op = ne_out + ((size_t)k * NEDGE + e) * DE;
#pragma unroll
    for (int c = 0; c < DE / 4; c++)
        ((float4*)op)[c] = make_float4(o[4 * c], o[4 * c + 1], o[4 * c + 2], o[4 * c + 3]);

    // ---- fused scatter-aggregate (sum + count) ----
    float* sums = ws;
    float* cnts = ws + (size_t)4 * WS_SUM;
    if (k == 0) {
        float* s = sums + (size_t)src * DE;
#pragma unroll
        for (int j = 0; j < DE; j++) atomicAdd(s + j, o[j]);
        atomicAdd(cnts + src, 1.0f);
    } else if (k == 1) {
        float* s = sums + WS_SUM + (size_t)src * DE;
#pragma unroll
        for (int j = 0; j < DE; j++) atomicAdd(s + j, o[j]);
        atomicAdd(cnts + NA + src, 1.0f);
        s = sums + (size_t)2 * WS_SUM + (size_t)dst * DE;
#pragma unroll
        for (int j = 0; j < DE; j++) atomicAdd(s + j, o[j]);
        atomicAdd(cnts + 2 * NA + dst, 1.0f);
    } else {
        float* s = sums + (size_t)3 * WS_SUM + (size_t)src * DE;
#pragma unroll
        for (int j = 0; j < DE; j++) atomicAdd(s + j, o[j]);
        atomicAdd(cnts + 3 * NA + src, 1.0f);
    }
}

__global__ __launch_bounds__(256) void node_kernel(
    const float* __restrict__ x_a, const float* __restrict__ x_b,
    const float* __restrict__ Wn1, const float* __restrict__ bn1,
    const float* __restrict__ Wn2, const float* __restrict__ bn2,
    float* __restrict__ out,       // d_out base: nx_a then nx_b
    const float* __restrict__ ws)
{
    constexpr int BPT = (NA + 255) / 256;
    const int t = blockIdx.x / BPT;           // node type 0=a 1=b (block-uniform)
    const int n = (blockIdx.x - t * BPT) * 256 + threadIdx.x;
    if (n >= NA) return;

    const float* x  = t ? x_b : x_a;
    const float* s1 = ws + (size_t)(2 * t)     * WS_SUM + (size_t)n * DE;
    const float* s2 = ws + (size_t)(2 * t + 1) * WS_SUM + (size_t)n * DE;
    const float* cnts = ws + (size_t)4 * WS_SUM;
    const float c1 = cnts[(size_t)(2 * t) * NA + n];
    const float c2 = cnts[(size_t)(2 * t + 1) * NA + n];
    const float inv1 = 1.0f / fmaxf(c1, 1.0f);
    const float inv2 = 1.0f / fmaxf(c2, 1.0f);

    const float* __restrict__ W1 = Wn1 + (size_t)t * (DN + 2 * DE) * DH;
    const float* __restrict__ W2 = Wn2 + (size_t)t * DH * DN;

    float h[DH];
#pragma unroll
    for (int j = 0; j < DH; j++) h[j] = bn1[t * DH + j];

    // x segment (rows 0..63 of W1)
    {
        const float4* row = (const float4*)(x + (size_t)n * DN);
        for (int c = 0; c < DN / 4; c++) {
            float4 v = row[c];
            const float* w = W1 + (size_t)(c * 4) * DH;
#pragma unroll
            for (int j = 0; j < DH; j++) h[j] = fmaf(v.x, w[j], h[j]);
#pragma unroll
            for (int j = 0; j < DH; j++) h[j] = fmaf(v.y, w[DH + j], h[j]);
#pragma unroll
            for (int j = 0; j < DH; j++) h[j] = fmaf(v.z, w[2 * DH + j], h[j]);
#pragma unroll
            for (int j = 0; j < DH; j++) h[j] = fmaf(v.w, w[3 * DH + j], h[j]);
        }
    }
    // mean-agg segment 1 (rows 64..95)
    {
        const float4* row = (const float4*)s1;
        for (int c = 0; c < DE / 4; c++) {
            float4 v = row[c];
            v.x *= inv1; v.y *= inv1; v.z *= inv1; v.w *= inv1;
            const float* w = W1 + (size_t)(DN + c * 4) * DH;
#pragma unroll
            for (int j = 0; j < DH; j++) h[j] = fmaf(v.x, w[j], h[j]);
#pragma unroll
            for (int j = 0; j < DH; j++) h[j] = fmaf(v.y, w[DH + j], h[j]);
#pragma unroll
            for (int j = 0; j < DH; j++) h[j] = fmaf(v.z, w[2 * DH + j], h[j]);
#pragma unroll
            for (int j = 0; j < DH; j++) h[j] = fmaf(v.w, w[3 * DH + j], h[j]);
        }
    }
    // mean-agg segment 2 (rows 96..127)
    {
        const float4* row = (const float4*)s2;
        for (int c = 0; c < DE / 4; c++) {
            float4 v = row[c];
            v.x *= inv2; v.y *= inv2; v.z *= inv2; v.w *= inv2;
            const float* w = W1 + (size_t)(DN + DE + c * 4) * DH;
#pragma unroll
            for (int j = 0; j < DH; j++) h[j] = fmaf(v.x, w[j], h[j]);
#pragma unroll
            for (int j = 0; j < DH; j++) h[j] = fmaf(v.y, w[DH + j], h[j]);
#pragma unroll
            for (int j = 0; j < DH; j++) h[j] = fmaf(v.z, w[2 * DH + j], h[j]);
#pragma unroll
            for (int j = 0; j < DH; j++) h[j] = fmaf(v.w, w[3 * DH + j], h[j]);
        }
    }

#pragma unroll
    for (int j = 0; j < DH; j++) h[j] = fmaxf(h[j], 0.f);

    float o[DN];
#pragma unroll
    for (int j = 0; j < DN; j++) o[j] = bn2[t * DN + j];
#pragma unroll
    for (int i = 0; i < DH; i++) {
        float v = h[i];
        const float* w = W2 + (size_t)i * DN;
#pragma unroll
        for (int j = 0; j < DN; j++) o[j] = fmaf(v, w[j], o[j]);
    }

    float* op = out + ((size_t)t * NA + n) * DN;
#pragma unroll
    for (int c = 0; c < DN / 4; c++)
        ((float4*)op)[c] = make_float4(o[4 * c], o[4 * c + 1], o[4 * c + 2], o[4 * c + 3]);
}

extern "C" void kernel_launch(void* const* d_in, const int* in_sizes, int n_in,
                              void* d_out, int out_size, void* d_ws, size_t ws_size,
                              hipStream_t stream)
{
    const float* x_a  = (const float*)d_in[0];
    const float* x_b  = (const float*)d_in[1];
    const int*   ei_aa = (const int*)d_in[2];
    const int*   ei_ab = (const int*)d_in[3];
    const int*   ei_bb = (const int*)d_in[4];
    const float* ea_aa = (const float*)d_in[5];
    const float* ea_ab = (const float*)d_in[6];
    const float* ea_bb = (const float*)d_in[7];
    const float* We1 = (const float*)d_in[8];
    const float* be1 = (const float*)d_in[9];
    const float* We2 = (const float*)d_in[10];
    const float* be2 = (const float*)d_in[11];
    const float* Wn1 = (const float*)d_in[12];
    const float* bn1 = (const float*)d_in[13];
    const float* Wn2 = (const float*)d_in[14];
    const float* bn2 = (const float*)d_in[15];

    float* out = (float*)d_out;
    float* ws  = (float*)d_ws;

    // zero aggregation workspace (re-poisoned to 0xAA before every launch)
    zero_ws<<<1024, 256, 0, stream>>>((float4*)ws, WS_FLOATS / 4);

    // edge MLPs + fused scatter-aggregate.  ne region starts after nx_a, nx_b.
    constexpr int BPT_E = (NEDGE + 255) / 256;
    edge_kernel<<<3 * BPT_E, 256, 0, stream>>>(
        x_a, x_b, ei_aa, ei_ab, ei_bb, ea_aa, ea_ab, ea_bb,
        We1, be1, We2, be2, out + (size_t)2 * NA * DN, ws);

    // node MLPs
    constexpr int BPT_N = (NA + 255) / 256;
    node_kernel<<<2 * BPT_N, 256, 0, stream>>>(
        x_a, x_b, Wn1, bn1, Wn2, bn2, out, ws);
}

// Round 2
// 677.466 us; speedup vs baseline: 5.0056x; 5.0056x over previous
//
#include <hip/hip_runtime.h>

// MetaLayer GNN on MI355X — round 2: bf16 MFMA (16x16x32) for both MLPs.
// Block = 256 threads (4 waves) handles 64 edges (or 64 nodes).
// Weights transposed to [n][k] bf16 in LDS once per block; features gathered
// to LDS as bf16; per-wave MFMA with fp32 accumulate; scatter-aggregate via
// fp32 global atomics (unchanged from round 1 — diagnostic control).

constexpr int NA = 100000;
constexpr int NEDGE = 400000;
constexpr int DN = 64;
constexpr int DE = 32;
constexpr int DH = 64;

constexpr int WS_SUM = NA * DE;           // 3.2M floats per sum buffer
constexpr int WS_FLOATS = 4 * WS_SUM + 4 * NA;

constexpr int FSTR = 168;  // edge concat-feature / W1^T stride (160 + 8 pad)
constexpr int NSTR = 136;  // node concat-feature / Wn1^T stride (128 + 8 pad)
constexpr int HSTR = 72;   // hidden / W2^T stride (64 + 8 pad)

typedef __bf16 bf16x8 __attribute__((ext_vector_type(8)));
typedef __bf16 bf16x4 __attribute__((ext_vector_type(4)));
typedef float f32x4 __attribute__((ext_vector_type(4)));

__global__ __launch_bounds__(256) void zero_ws(float4* __restrict__ ws, int n4) {
    int i = blockIdx.x * 256 + threadIdx.x;
    int stride = gridDim.x * 256;
    for (; i < n4; i += stride) ws[i] = make_float4(0.f, 0.f, 0.f, 0.f);
}

// ---------------- edge kernel ----------------
__global__ __launch_bounds__(256) void edge_kernel(
    const float* __restrict__ x_a, const float* __restrict__ x_b,
    const int* __restrict__ ei_aa, const int* __restrict__ ei_ab, const int* __restrict__ ei_bb,
    const float* __restrict__ ea_aa, const float* __restrict__ ea_ab, const float* __restrict__ ea_bb,
    const float* __restrict__ We1, const float* __restrict__ be1,
    const float* __restrict__ We2, const float* __restrict__ be2,
    float* __restrict__ ne_out,   // 3 ne arrays back-to-back, [3*NEDGE][32]
    float* __restrict__ ws)
{
    __shared__ __bf16 feat[64 * FSTR];   // concat features, [64 edges][160]
    __shared__ __bf16 w1T [64 * FSTR];   // W1^T [n=64][k=160]
    __shared__ __bf16 w2T [32 * HSTR];   // W2^T [n=32][k=64]
    __shared__ int sidx[64], didx[64];

    const int tid = threadIdx.x;
    constexpr int BPT = NEDGE / 64;      // 6250 blocks per edge type
    const int k   = blockIdx.x / BPT;    // edge type (block-uniform)
    const int blk = blockIdx.x % BPT;

    const int*   ei = (k == 0) ? ei_aa : (k == 1) ? ei_ab : ei_bb;
    const float* ea = (k == 0) ? ea_aa : (k == 1) ? ea_ab : ea_bb;
    const float* x1 = (k == 2) ? x_b : x_a;
    const float* x2 = (k == 0) ? x_a : x_b;
    const float* __restrict__ W1 = We1 + (size_t)k * (2 * DN + DE) * DH;
    const float* __restrict__ W2 = We2 + (size_t)k * DH * DE;

    // ---- stage weights transposed, f32 -> bf16 ----
    for (int i = tid; i < 160 * 64; i += 256) {
        int r = i >> 6, c = i & 63;              // W1[r][c], coalesced read
        w1T[c * FSTR + r] = (__bf16)W1[i];
    }
    for (int i = tid; i < 64 * 32; i += 256) {
        int r = i >> 5, c = i & 31;              // W2[r][c]
        w2T[c * HSTR + r] = (__bf16)W2[i];
    }

    // ---- gather + convert concat features: 4 threads per edge ----
    {
        const int q = tid & 3, el = tid >> 2;
        const int e = blk * 64 + el;
        const int src = ei[e];
        const int dst = ei[NEDGE + e];
        if (q == 0) { sidx[el] = src; didx[el] = dst; }

        const float4* p1 = (const float4*)(x1 + (size_t)src * DN);
        const float4* p2 = (const float4*)(x2 + (size_t)dst * DN);
        const float4* pe = (const float4*)(ea + (size_t)e * DE);
#pragma unroll
        for (int i = 0; i < 4; i++) {
            float4 v = p1[q * 4 + i];
            bf16x4 t = {(__bf16)v.x, (__bf16)v.y, (__bf16)v.z, (__bf16)v.w};
            *(bf16x4*)&feat[el * FSTR + q * 16 + i * 4] = t;
        }
#pragma unroll
        for (int i = 0; i < 4; i++) {
            float4 v = p2[q * 4 + i];
            bf16x4 t = {(__bf16)v.x, (__bf16)v.y, (__bf16)v.z, (__bf16)v.w};
            *(bf16x4*)&feat[el * FSTR + 64 + q * 16 + i * 4] = t;
        }
#pragma unroll
        for (int i = 0; i < 2; i++) {
            float4 v = pe[q * 2 + i];
            bf16x4 t = {(__bf16)v.x, (__bf16)v.y, (__bf16)v.z, (__bf16)v.w};
            *(bf16x4*)&feat[el * FSTR + 128 + q * 8 + i * 4] = t;
        }
        // degree counts (one per edge-target)
        if (q == 0) {
            float* cnt = ws + (size_t)4 * WS_SUM;
            if (k == 0)      atomicAdd(cnt + src, 1.0f);
            else if (k == 1) { atomicAdd(cnt + NA + src, 1.0f);
                               atomicAdd(cnt + 2 * NA + dst, 1.0f); }
            else             atomicAdd(cnt + 3 * NA + src, 1.0f);
        }
    }
    __syncthreads();

    const int w = tid >> 6, lane = tid & 63;
    const int m16 = lane & 15, quad = lane >> 4;

    // ---- layer 1: h[64 edges][64] = feat @ W1 ; wave w owns cols 16w..16w+16
    f32x4 acc0 = {0.f,0.f,0.f,0.f}, acc1 = acc0, acc2v = acc0, acc3 = acc0;
    for (int kk = 0; kk < 5; kk++) {
        bf16x8 b = *(const bf16x8*)&w1T[(w * 16 + m16) * FSTR + kk * 32 + quad * 8];
        bf16x8 a0 = *(const bf16x8*)&feat[( 0 + m16) * FSTR + kk * 32 + quad * 8];
        bf16x8 a1 = *(const bf16x8*)&feat[(16 + m16) * FSTR + kk * 32 + quad * 8];
        bf16x8 a2 = *(const bf16x8*)&feat[(32 + m16) * FSTR + kk * 32 + quad * 8];
        bf16x8 a3 = *(const bf16x8*)&feat[(48 + m16) * FSTR + kk * 32 + quad * 8];
        acc0 = __builtin_amdgcn_mfma_f32_16x16x32_bf16(a0, b, acc0, 0, 0, 0);
        acc1 = __builtin_amdgcn_mfma_f32_16x16x32_bf16(a1, b, acc1, 0, 0, 0);
        acc2v = __builtin_amdgcn_mfma_f32_16x16x32_bf16(a2, b, acc2v, 0, 0, 0);
        acc3 = __builtin_amdgcn_mfma_f32_16x16x32_bf16(a3, b, acc3, 0, 0, 0);
    }
    const float b1c = be1[k * DH + w * 16 + m16];
    __syncthreads();                 // all feat reads done before aliasing
    __bf16* hbuf = feat;             // reuse feat LDS: h [64 edges][64], stride HSTR
    {
        f32x4 av[4] = {acc0, acc1, acc2v, acc3};
#pragma unroll
        for (int mt = 0; mt < 4; mt++)
#pragma unroll
            for (int r = 0; r < 4; r++) {
                float v = av[mt][r] + b1c;
                v = fmaxf(v, 0.f);
                hbuf[(mt * 16 + quad * 4 + r) * HSTR + w * 16 + m16] = (__bf16)v;
            }
    }
    __syncthreads();

    // ---- layer 2: o[64][32] = relu(h) @ W2 ; wave w owns edge rows 16w..16w+16
    f32x4 o0 = {0.f,0.f,0.f,0.f}, o1 = o0;
#pragma unroll
    for (int kk = 0; kk < 2; kk++) {
        bf16x8 a = *(const bf16x8*)&hbuf[(w * 16 + m16) * HSTR + kk * 32 + quad * 8];
        bf16x8 bb0 = *(const bf16x8*)&w2T[( 0 + m16) * HSTR + kk * 32 + quad * 8];
        bf16x8 bb1 = *(const bf16x8*)&w2T[(16 + m16) * HSTR + kk * 32 + quad * 8];
        o0 = __builtin_amdgcn_mfma_f32_16x16x32_bf16(a, bb0, o0, 0, 0, 0);
        o1 = __builtin_amdgcn_mfma_f32_16x16x32_bf16(a, bb1, o1, 0, 0, 0);
    }

    // ---- epilogue: write ne + scatter-aggregate ----
    float* sums = ws;
#pragma unroll
    for (int nt = 0; nt < 2; nt++) {
        const int col = nt * 16 + m16;
        const float b2c = be2[k * DE + col];
        const f32x4 oo = nt ? o1 : o0;
#pragma unroll
        for (int r = 0; r < 4; r++) {
            const int er = w * 16 + quad * 4 + r;        // local edge row
            const float v = oo[r] + b2c;
            ne_out[((size_t)k * NEDGE + blk * 64 + er) * DE + col] = v;
            if (k == 0) {
                atomicAdd(&sums[(size_t)sidx[er] * DE + col], v);
            } else if (k == 1) {
                atomicAdd(&sums[WS_SUM + (size_t)sidx[er] * DE + col], v);
                atomicAdd(&sums[(size_t)2 * WS_SUM + (size_t)didx[er] * DE + col], v);
            } else {
                atomicAdd(&sums[(size_t)3 * WS_SUM + (size_t)sidx[er] * DE + col], v);
            }
        }
    }
}

// ---------------- node kernel ----------------
__global__ __launch_bounds__(256) void node_kernel(
    const float* __restrict__ x_a, const float* __restrict__ x_b,
    const float* __restrict__ Wn1, const float* __restrict__ bn1,
    const float* __restrict__ Wn2, const float* __restrict__ bn2,
    float* __restrict__ out,      // nx_a then nx_b, [2*NA][64]
    const float* __restrict__ ws)
{
    __shared__ __bf16 feat[64 * NSTR];   // concat features [64 nodes][128]
    __shared__ __bf16 w1T [64 * NSTR];   // Wn1^T [n=64][k=128]
    __shared__ __bf16 w2T [64 * HSTR];   // Wn2^T [n=64][k=64]

    const int tid = threadIdx.x;
    constexpr int BPT = (NA + 63) / 64;  // 1563
    const int t   = blockIdx.x / BPT;    // node type (block-uniform)
    const int blk = blockIdx.x % BPT;

    const float* x = t ? x_b : x_a;
    const float* __restrict__ W1 = Wn1 + (size_t)t * (DN + 2 * DE) * DH;
    const float* __restrict__ W2 = Wn2 + (size_t)t * DH * DN;

    for (int i = tid; i < 128 * 64; i += 256) {
        int r = i >> 6, c = i & 63;
        w1T[c * NSTR + r] = (__bf16)W1[i];
    }
    for (int i = tid; i < 64 * 64; i += 256) {
        int r = i >> 6, c = i & 63;
        w2T[c * HSTR + r] = (__bf16)W2[i];
    }

    // ---- gather concat features: x | mean1 | mean2 ----
    {
        const int q = tid & 3, nl = tid >> 2;
        const int n = blk * 64 + nl;
        const int ng = (n < NA) ? n : NA - 1;
        const float* cnt = ws + (size_t)4 * WS_SUM;
        const float inv1 = 1.0f / fmaxf(cnt[(size_t)(2 * t) * NA + ng], 1.0f);
        const float inv2 = 1.0f / fmaxf(cnt[(size_t)(2 * t + 1) * NA + ng], 1.0f);

        const float4* px = (const float4*)(x + (size_t)ng * DN);
        const float4* p1 = (const float4*)(ws + (size_t)(2 * t) * WS_SUM + (size_t)ng * DE);
        const float4* p2 = (const float4*)(ws + (size_t)(2 * t + 1) * WS_SUM + (size_t)ng * DE);
#pragma unroll
        for (int i = 0; i < 4; i++) {
            float4 v = px[q * 4 + i];
            bf16x4 tt = {(__bf16)v.x, (__bf16)v.y, (__bf16)v.z, (__bf16)v.w};
            *(bf16x4*)&feat[nl * NSTR + q * 16 + i * 4] = tt;
        }
#pragma unroll
        for (int i = 0; i < 2; i++) {
            float4 v = p1[q * 2 + i];
            bf16x4 tt = {(__bf16)(v.x * inv1), (__bf16)(v.y * inv1),
                         (__bf16)(v.z * inv1), (__bf16)(v.w * inv1)};
            *(bf16x4*)&feat[nl * NSTR + 64 + q * 8 + i * 4] = tt;
        }
#pragma unroll
        for (int i = 0; i < 2; i++) {
            float4 v = p2[q * 2 + i];
            bf16x4 tt = {(__bf16)(v.x * inv2), (__bf16)(v.y * inv2),
                         (__bf16)(v.z * inv2), (__bf16)(v.w * inv2)};
            *(bf16x4*)&feat[nl * NSTR + 96 + q * 8 + i * 4] = tt;
        }
    }
    __syncthreads();

    const int w = tid >> 6, lane = tid & 63;
    const int m16 = lane & 15, quad = lane >> 4;

    // ---- layer 1: h = feat[64][128] @ Wn1 ; wave w owns cols 16w..16w+16
    f32x4 acc0 = {0.f,0.f,0.f,0.f}, acc1 = acc0, acc2v = acc0, acc3 = acc0;
#pragma unroll
    for (int kk = 0; kk < 4; kk++) {
        bf16x8 b = *(const bf16x8*)&w1T[(w * 16 + m16) * NSTR + kk * 32 + quad * 8];
        bf16x8 a0 = *(const bf16x8*)&feat[( 0 + m16) * NSTR + kk * 32 + quad * 8];
        bf16x8 a1 = *(const bf16x8*)&feat[(16 + m16) * NSTR + kk * 32 + quad * 8];
        bf16x8 a2 = *(const bf16x8*)&feat[(32 + m16) * NSTR + kk * 32 + quad * 8];
        bf16x8 a3 = *(const bf16x8*)&feat[(48 + m16) * NSTR + kk * 32 + quad * 8];
        acc0 = __builtin_amdgcn_mfma_f32_16x16x32_bf16(a0, b, acc0, 0, 0, 0);
        acc1 = __builtin_amdgcn_mfma_f32_16x16x32_bf16(a1, b, acc1, 0, 0, 0);
        acc2v = __builtin_amdgcn_mfma_f32_16x16x32_bf16(a2, b, acc2v, 0, 0, 0);
        acc3 = __builtin_amdgcn_mfma_f32_16x16x32_bf16(a3, b, acc3, 0, 0, 0);
    }
    const float b1c = bn1[t * DH + w * 16 + m16];
    __syncthreads();
    __bf16* hbuf = feat;             // alias, h [64 nodes][64], stride HSTR
    {
        f32x4 av[4] = {acc0, acc1, acc2v, acc3};
#pragma unroll
        for (int mt = 0; mt < 4; mt++)
#pragma unroll
            for (int r = 0; r < 4; r++) {
                float v = av[mt][r] + b1c;
                v = fmaxf(v, 0.f);
                hbuf[(mt * 16 + quad * 4 + r) * HSTR + w * 16 + m16] = (__bf16)v;
            }
    }
    __syncthreads();

    // ---- layer 2: nx[64][64] = relu(h) @ Wn2 ; wave w owns node rows 16w..
    f32x4 o0 = {0.f,0.f,0.f,0.f}, o1 = o0, o2 = o0, o3 = o0;
#pragma unroll
    for (int kk = 0; kk < 2; kk++) {
        bf16x8 a = *(const bf16x8*)&hbuf[(w * 16 + m16) * HSTR + kk * 32 + quad * 8];
        bf16x8 bb0 = *(const bf16x8*)&w2T[( 0 + m16) * HSTR + kk * 32 + quad * 8];
        bf16x8 bb1 = *(const bf16x8*)&w2T[(16 + m16) * HSTR + kk * 32 + quad * 8];
        bf16x8 bb2 = *(const bf16x8*)&w2T[(32 + m16) * HSTR + kk * 32 + quad * 8];
        bf16x8 bb3 = *(const bf16x8*)&w2T[(48 + m16) * HSTR + kk * 32 + quad * 8];
        o0 = __builtin_amdgcn_mfma_f32_16x16x32_bf16(a, bb0, o0, 0, 0, 0);
        o1 = __builtin_amdgcn_mfma_f32_16x16x32_bf16(a, bb1, o1, 0, 0, 0);
        o2 = __builtin_amdgcn_mfma_f32_16x16x32_bf16(a, bb2, o2, 0, 0, 0);
        o3 = __builtin_amdgcn_mfma_f32_16x16x32_bf16(a, bb3, o3, 0, 0, 0);
    }
#pragma unroll
    for (int nt = 0; nt < 4; nt++) {
        const int col = nt * 16 + m16;
        const float b2c = bn2[t * DN + col];
        const f32x4 oo = (nt == 0) ? o0 : (nt == 1) ? o1 : (nt == 2) ? o2 : o3;
#pragma unroll
        for (int r = 0; r < 4; r++) {
            const int n = blk * 64 + w * 16 + quad * 4 + r;
            if (n < NA)
                out[((size_t)t * NA + n) * DN + col] = oo[r] + b2c;
        }
    }
}

extern "C" void kernel_launch(void* const* d_in, const int* in_sizes, int n_in,
                              void* d_out, int out_size, void* d_ws, size_t ws_size,
                              hipStream_t stream)
{
    const float* x_a  = (const float*)d_in[0];
    const float* x_b  = (const float*)d_in[1];
    const int*   ei_aa = (const int*)d_in[2];
    const int*   ei_ab = (const int*)d_in[3];
    const int*   ei_bb = (const int*)d_in[4];
    const float* ea_aa = (const float*)d_in[5];
    const float* ea_ab = (const float*)d_in[6];
    const float* ea_bb = (const float*)d_in[7];
    const float* We1 = (const float*)d_in[8];
    const float* be1 = (const float*)d_in[9];
    const float* We2 = (const float*)d_in[10];
    const float* be2 = (const float*)d_in[11];
    const float* Wn1 = (const float*)d_in[12];
    const float* bn1 = (const float*)d_in[13];
    const float* Wn2 = (const float*)d_in[14];
    const float* bn2 = (const float*)d_in[15];

    float* out = (float*)d_out;
    float* ws  = (float*)d_ws;

    zero_ws<<<1024, 256, 0, stream>>>((float4*)ws, WS_FLOATS / 4);

    constexpr int BPT_E = NEDGE / 64;        // 6250
    edge_kernel<<<3 * BPT_E, 256, 0, stream>>>(
        x_a, x_b, ei_aa, ei_ab, ei_bb, ea_aa, ea_ab, ea_bb,
        We1, be1, We2, be2, out + (size_t)2 * NA * DN, ws);

    constexpr int BPT_N = (NA + 63) / 64;    // 1563
    node_kernel<<<2 * BPT_N, 256, 0, stream>>>(
        x_a, x_b, Wn1, bn1, Wn2, bn2, out, ws);
}